// Round 13
// baseline (321.758 us; speedup 1.0000x reference)
//
#include <hip/hip_runtime.h>

// ---------------------------------------------------------------------------
// Cascade MLP, MI355X. fp16 hi/lo split GEMMs (3 passes, fp32 accum).
// FRAGMENT-MAJOR layouts; zero LDS bank conflicts (r9-verified).
// Round-13: p1 x-path rebuilt for DRAM request contiguity. Old: each x-load =
// 16 rows x 64B (stride 12KB) -> ~65% HBM efficiency (r12 measured ~9750
// cyc/step vs 6400 floor). New: 512 blk x 512 thr x 128 rows; each x-load
// instruction = 4 rows x 256B contiguous; regs -> split fp16 hi/lo ->
// ds_write scatter into swizzled fragment-major x image in LDS (write 4-way,
// reads lane-linear conflict-free). Same kappa k-permutation as the W1
// A-frags (absmax canary: must stay exactly 2.441406e-4).
// Pipeline: C(s)=[W(s+1)->Wbuf[(s+1)&1], x(s+3)->regs]; A(s) vmcnt(4)
// (tail=x(s+2)); x cvt+write between the two barriers. LDS 128KB, 8 waves.
// p2 / prep: unchanged from round 12.
// ---------------------------------------------------------------------------

typedef __fp16 h2   __attribute__((ext_vector_type(2)));
typedef __fp16 h8v  __attribute__((ext_vector_type(8)));
typedef float  f4v  __attribute__((ext_vector_type(4)));
typedef float  f16v __attribute__((ext_vector_type(16)));

#define CHUNK 16384   // one fragment-major k-chunk: 16 fragments x 1KB

static constexpr unsigned OFF_W1  = 0;                       // 96 chunks
static constexpr unsigned OFF_WH  = 96u * CHUNK;             // 1572864, 56 chunks
static constexpr unsigned OFF_WO  = OFF_WH + 56u * CHUNK;    // 2490368, 3 chunks
static constexpr unsigned OFF_BIN = OFF_WO + 3u * CHUNK;     // 2539520, 128 f32
static constexpr unsigned OFF_H1  = OFF_BIN + 512;           // 2540032, 512 x 64KB

__device__ __forceinline__ unsigned bc2(h2 v) { return __builtin_bit_cast(unsigned, v); }

__device__ __forceinline__ f4v ntld4(const float* p) {
  return __builtin_nontemporal_load((const f4v*)p);
}

__device__ __forceinline__ void lds_cp16(const char* g, char* l) {
  __builtin_amdgcn_global_load_lds(
      (const __attribute__((address_space(1))) void*)g,
      (__attribute__((address_space(3))) void*)l, 16, 0, 0);
}

// p2: stage one 16KB chunk with 512 threads (2 x 16B per thread)
__device__ __forceinline__ void stage2(const char* g, char* l, int tid) {
  lds_cp16(g + tid * 16, l + tid * 16);
  lds_cp16(g + 8192 + tid * 16, l + 8192 + tid * 16);
}

// f4v -> hi 8B + lo 8B (plain split, no relu)
__device__ __forceinline__ void split4s(f4v v, uint2& hi, uint2& lo) {
  h2 a = __builtin_amdgcn_cvt_pkrtz(v[0], v[1]);
  h2 b = __builtin_amdgcn_cvt_pkrtz(v[2], v[3]);
  h2 c = __builtin_amdgcn_cvt_pkrtz(v[0] - (float)a[0], v[1] - (float)a[1]);
  h2 d = __builtin_amdgcn_cvt_pkrtz(v[2] - (float)b[0], v[3] - (float)b[1]);
  hi = make_uint2(bc2(a), bc2(b));
  lo = make_uint2(bc2(c), bc2(d));
}

__device__ __forceinline__ void split8w(const float* f, uint4& hi, uint4& lo) {
  h2 h0 = __builtin_amdgcn_cvt_pkrtz(f[0], f[1]);
  h2 h1 = __builtin_amdgcn_cvt_pkrtz(f[2], f[3]);
  h2 h2_ = __builtin_amdgcn_cvt_pkrtz(f[4], f[5]);
  h2 h3 = __builtin_amdgcn_cvt_pkrtz(f[6], f[7]);
  h2 l0 = __builtin_amdgcn_cvt_pkrtz(f[0] - (float)h0[0], f[1] - (float)h0[1]);
  h2 l1 = __builtin_amdgcn_cvt_pkrtz(f[2] - (float)h1[0], f[3] - (float)h1[1]);
  h2 l2 = __builtin_amdgcn_cvt_pkrtz(f[4] - (float)h2_[0], f[5] - (float)h2_[1]);
  h2 l3 = __builtin_amdgcn_cvt_pkrtz(f[6] - (float)h3[0], f[7] - (float)h3[1]);
  hi = make_uint4(bc2(h0), bc2(h1), bc2(h2_), bc2(h3));
  lo = make_uint4(bc2(l0), bc2(l1), bc2(l2), bc2(l3));
}

// flat items: L0-3=0..15, head0=16, L4-8=17..36, head1=37, L9-13=38..57, head2=58
__device__ __forceinline__ unsigned item_off(int it) {
  if (it >= 58) return OFF_WO + 2u * CHUNK;   // 58 + dummy tails
  if (it == 16) return OFF_WO;
  if (it == 37) return OFF_WO + CHUNK;
  int j = it - (it > 16 ? 1 : 0) - (it > 37 ? 1 : 0);
  return OFF_WH + (unsigned)j * CHUNK;
}

// ---------------------------------------------------------------------------
// prep: fragment-major images (unchanged from round 12).
// ---------------------------------------------------------------------------
__global__ __launch_bounds__(256) void prep_k(
    const float* __restrict__ w_in, const float* __restrict__ b_in,
    const float* __restrict__ w_hid, const float* __restrict__ b_hid,
    const float* __restrict__ w_out, const float* __restrict__ b_out,
    char* __restrict__ ws) {
  int idx = blockIdx.x * 256 + threadIdx.x;
  int lane = idx & 63;
  int grp = idx >> 6;
  float f[8];
  uint4 hi, lo;
  if (grp < 768) {  // W1: c(96) x mf(8) 16x16x32 A-frags, kappa k-perm
    int mf = grp & 7, c = grp >> 3;
    int feat = mf * 16 + (lane & 15);
    int g = lane >> 4;
    int kb = c * 32 + g * 4;
#pragma unroll
    for (int e = 0; e < 8; ++e) {
      int k = kb + (e < 4 ? e : 12 + e);   // kappa(g,e): e>=4 -> +16
      f[e] = (feat < 100) ? w_in[(size_t)k * 100 + feat] : 0.f;
    }
    split8w(f, hi, lo);
    char* dst = ws + OFF_W1 + (size_t)c * CHUNK + (size_t)mf * 2048 + lane * 16;
    *(uint4*)dst = hi;
    *(uint4*)(dst + 1024) = lo;
    return;
  }
  grp -= 768;
  if (grp < 448) {  // WH: ch(56 = L*4+s) x ft(4) x j(2), 32x32 frags; bias @k=127
    int j = grp & 1, ft = (grp >> 1) & 3, ch = grp >> 3;
    int L = ch >> 2, s = ch & 3;
    int feat = ft * 32 + (lane & 31);
    int k0 = s * 32 + j * 16 + (lane >> 5) * 8;
#pragma unroll
    for (int e = 0; e < 8; ++e) {
      int k = k0 + e;
      float v;
      if (k < 100 && feat < 100)  v = w_hid[(size_t)L * 10000 + k * 100 + feat];
      else if (k == 127)          v = (feat < 100) ? b_hid[L * 100 + feat]
                                                   : (feat == 127 ? 1.f : 0.f);
      else                        v = 0.f;
      f[e] = v;
    }
    split8w(f, hi, lo);
    char* dst = ws + OFF_WH + (size_t)ch * CHUNK + (size_t)((ft * 2 + j) * 2) * 1024 + lane * 16;
    *(uint4*)dst = hi;
    *(uint4*)(dst + 1024) = lo;
    return;
  }
  grp -= 448;
  if (grp < 24) {  // WO: st(3) x kblk(8); bias row k=127, pad classes -60000
    int kb = grp & 7, st = grp >> 3;
    int cls = lane & 31;
    int k0 = kb * 16 + (lane >> 5) * 8;
#pragma unroll
    for (int e = 0; e < 8; ++e) {
      int k = k0 + e;
      float v;
      if (cls < 10 && k < 100) v = w_out[(size_t)st * 1000 + k * 10 + cls];
      else if (k == 127)       v = (cls < 10) ? b_out[st * 10 + cls] : -60000.f;
      else                     v = 0.f;
      f[e] = v;
    }
    split8w(f, hi, lo);
    char* dst = ws + OFF_WO + (size_t)st * CHUNK + (size_t)(kb * 2) * 1024 + lane * 16;
    *(uint4*)dst = hi;
    *(uint4*)(dst + 1024) = lo;
    return;
  }
  grp -= 24;
  if (grp < 2) {  // BIN: p1 epilogue bias (128 f32), bin[127] = 1.0
    int i = grp * 64 + lane;
    ((float*)(ws + OFF_BIN))[i] = (i < 100) ? b_in[i] : (i == 127 ? 1.f : 0.f);
  }
}

// ---------------------------------------------------------------------------
// p1: h1 = relu(x @ w_in + b_in) -> fragment-major h image in ws.
// 512 blocks x 512 thr (8 waves x 16 rows). BK=64. x: contiguous 4x256B
// loads -> regs -> fp16 split -> ds_write into swizzled frag-major LDS image.
// ---------------------------------------------------------------------------
#define P1_SMEM 131072  // xbuf 2x32KB @0; Wbuf 2x32KB @65536

__global__ __launch_bounds__(512, 2) void p1_k(const float* __restrict__ x,
                                               char* __restrict__ ws) {
  extern __shared__ __align__(16) char sm[];
  char* xbuf = sm;            // 2 x 32768 (frag-major f16 x image)
  char* wbuf = sm + 65536;    // 2 x 32768 (W chunk pairs)

  const int tid = threadIdx.x;
  const int lane = tid & 63, wid = tid >> 6;   // wid 0..7
  const int g = lane >> 4;                     // 0..3 (row-sub on load side)
  const int j = lane & 15;                     // k-chunk on load side
  const int tile = blockIdx.x;                 // 128 rows
  const char* w1g = ws + OFF_W1;

  // x sources: instruction q covers rows (wid*16 + q*4 .. +3) x 256B contig
  const float* xr[4];
#pragma unroll
  for (int q = 0; q < 4; ++q)
    xr[q] = x + (size_t)(tile * 128 + wid * 16 + q * 4 + g) * 3072 + j * 4;

  // x write dest offsets (frag-major, swizzled phi = fl ^ (gw<<2))
  int xwo[4];
  {
    const int kc = j >> 3, jj = j & 7, gw = jj & 3, half = jj >> 2;
#pragma unroll
    for (int q = 0; q < 4; ++q) {
      const int r = q * 4 + g;
      const int fl = gw * 16 + r;
      const int phi = fl ^ (gw << 2);
      xwo[q] = wid * 4096 + kc * 2048 + phi * 16 + half * 8;
    }
  }
  // B-frag read offset (same swizzle)
  const int xro = wid * 4096 + (lane ^ ((lane >> 4) << 2)) * 16;

  auto stW = [&](int s1, int b) {  // stage W chunk pair for step s1
    const char* gsrc = w1g + (size_t)(2 * s1) * CHUNK;
    char* dst = wbuf + b * 32768;
#pragma unroll
    for (int i = 0; i < 4; ++i)
      lds_cp16(gsrc + i * 8192 + tid * 16, dst + i * 8192 + tid * 16);
  };
  auto ldx = [&](int s1, f4v (&xa)[4]) {
    const int o = s1 * 64;
#pragma unroll
    for (int q = 0; q < 4; ++q) xa[q] = ntld4(xr[q] + o);
  };
  auto wrx = [&](int s1, f4v (&xa)[4]) {  // cvt + scatter into xbuf[s1&1]
    char* base = xbuf + (s1 & 1) * 32768;
#pragma unroll
    for (int q = 0; q < 4; ++q) {
      uint2 hi, lo;
      split4s(xa[q], hi, lo);
      char* d = base + xwo[q];
      *(uint2*)d = hi;
      *(uint2*)(d + 1024) = lo;
    }
  };

  f4v xP[4], xQ[4];
  // prologue: issue [x(0), W(0), x(1)]; drain x(0); write xbuf0; issue x(2)
  ldx(0, xP);
  __builtin_amdgcn_sched_barrier(0);
  stW(0, 0);
  __builtin_amdgcn_sched_barrier(0);
  ldx(1, xQ);
  __builtin_amdgcn_sched_barrier(0);
  asm volatile("s_waitcnt vmcnt(8)" ::: "memory");
  wrx(0, xP);
  __builtin_amdgcn_sched_barrier(0);
  ldx(2, xP);
  __builtin_amdgcn_sched_barrier(0);
  asm volatile("s_waitcnt lgkmcnt(0)" ::: "memory");

  f4v acc[8] = {};

  // steady: A(s) FIFO = [x(s+1), W(s), x(s+2)] -> vmcnt(4); s>=46 -> 0
  auto step = [&](int s, f4v (&xa)[4]) {
    if (s >= 46) asm volatile("s_waitcnt vmcnt(0)" ::: "memory");
    else         asm volatile("s_waitcnt vmcnt(4)" ::: "memory");
    __builtin_amdgcn_s_barrier();
    asm volatile("" ::: "memory");

    if (s < 47) wrx(s + 1, xa);           // cvt x(s+1) -> xbuf[(s+1)&1]
    __builtin_amdgcn_sched_barrier(0);
    if (s + 1 < 48) stW(s + 1, (s + 1) & 1);
    __builtin_amdgcn_sched_barrier(0);
    if (s + 3 < 48) ldx(s + 3, xa);       // reuse same reg set (parity match)
    __builtin_amdgcn_sched_barrier(0);
    asm volatile("s_waitcnt lgkmcnt(0)" ::: "memory");
    __builtin_amdgcn_s_barrier();
    asm volatile("" ::: "memory");

    const char* xb = xbuf + (s & 1) * 32768 + xro;
    const char* ab = wbuf + (s & 1) * 32768 + lane * 16;
#pragma unroll
    for (int kc = 0; kc < 2; ++kc) {
      h8v bh = *(const h8v*)(xb + kc * 2048);
      h8v bl = *(const h8v*)(xb + kc * 2048 + 1024);
#pragma unroll
      for (int mf = 0; mf < 8; ++mf) {
        h8v ahi = *(const h8v*)(ab + kc * 16384 + mf * 2048);
        h8v alo = *(const h8v*)(ab + kc * 16384 + mf * 2048 + 1024);
        acc[mf] = __builtin_amdgcn_mfma_f32_16x16x32_f16(ahi, bh, acc[mf], 0, 0, 0);
        acc[mf] = __builtin_amdgcn_mfma_f32_16x16x32_f16(ahi, bl, acc[mf], 0, 0, 0);
        acc[mf] = __builtin_amdgcn_mfma_f32_16x16x32_f16(alo, bh, acc[mf], 0, 0, 0);
      }
    }
  };

#pragma unroll 1
  for (int s2 = 0; s2 < 48; s2 += 2) {
    step(s2, xQ);      // x(s+1) odd -> xQ
    step(s2 + 1, xP);  // x(s+1) even -> xP
  }

  // epilogue: bias + relu + split -> global h frags (16x16 C/D).
  // Global row R = tile*128 + wid*16 + l15; feature = mf*16 + g*4 + q.
  const int l15 = lane & 15;
  const float* bp = (const float*)(ws + OFF_BIN);
  const int rt = wid >> 1;
  const int l31 = (wid & 1) * 16 + l15;
  char* hb = ws + OFF_H1 + (size_t)tile * 65536;
#pragma unroll
  for (int mf = 0; mf < 8; ++mf) {
    f4v bi = *(const f4v*)(bp + mf * 16 + g * 4);
    f4v v = acc[mf] + bi;
    v[0] = fmaxf(v[0], 0.f); v[1] = fmaxf(v[1], 0.f);
    v[2] = fmaxf(v[2], 0.f); v[3] = fmaxf(v[3], 0.f);
    uint2 hi, lo;
    split4s(v, hi, lo);
    char* dst = hb + (size_t)(rt * 8 + mf) * 2048 + (g >> 1) * 512 + l31 * 16 + (g & 1) * 8;
    *(uint2*)dst = hi;
    *(uint2*)(dst + 1024) = lo;
  }
}

// ---------------------------------------------------------------------------
// p2: cascade + heads + early-exit select (unchanged from round 12).
// ---------------------------------------------------------------------------
#define P2_SMEM (65536 + 4 * CHUNK)  // 131072

__global__ __launch_bounds__(512, 2) void p2_k(char* __restrict__ ws,
                                               float* __restrict__ out) {
  extern __shared__ __align__(16) char sm[];
  char* hsm = sm;             // h frags, 64KB
  char* wsm = sm + 65536;     // 4 chunk bufs
  const int tid = threadIdx.x;
  const int lane = tid & 63, wid = tid >> 6;
  const int mr = wid & 1, rt = wid >> 1;
  const int l31 = lane & 31, gg = lane >> 5;
  const int tile = blockIdx.x;

  {  // prologue DMA (per-lane FIFO): h(8), i0(2), i1(2), i2(2)
    const char* hg = ws + OFF_H1 + (size_t)tile * 65536;
#pragma unroll
    for (int i = 0; i < 8; ++i)
      lds_cp16(hg + i * 8192 + tid * 16, hsm + i * 8192 + tid * 16);
    __builtin_amdgcn_sched_barrier(0);
    stage2(ws + item_off(0), wsm, tid);
    stage2(ws + item_off(1), wsm + CHUNK, tid);
    stage2(ws + item_off(2), wsm + 2 * CHUNK, tid);
  }

  const f16v z16 = {};
  f16v a0 = {}, a1 = {};
  float s0[6], s1[6], s2[6];
  bool c0 = false, c1 = false;

  auto ring_top = [&](int i) {
    asm volatile("s_waitcnt vmcnt(4)" ::: "memory");
    __builtin_amdgcn_s_barrier();
    asm volatile("" ::: "memory");
    stage2(ws + item_off(i + 3), wsm + ((i + 3) & 3) * CHUNK, tid);
  };

  auto hidden = [&](int base) {
#pragma unroll
    for (int ss = 0; ss < 4; ++ss) {
      ring_top(base + ss);
      const char* wb = wsm + ((base + ss) & 3) * CHUNK + lane * 16;
      const char* hbp = hsm + rt * 16384 + ss * 4096 + lane * 16;
      h8v bh0 = *(const h8v*)(hbp);
      h8v bl0 = *(const h8v*)(hbp + 1024);
      h8v bh1 = *(const h8v*)(hbp + 2048);
      h8v bl1 = *(const h8v*)(hbp + 3072);
      const char* ab0 = wb + (mr * 2) * 4096;
      const char* ab1 = ab0 + 4096;
      h8v ah, al;
      ah = *(const h8v*)(ab0);        al = *(const h8v*)(ab0 + 1024);
      a0 = __builtin_amdgcn_mfma_f32_32x32x16_f16(ah, bh0, a0, 0, 0, 0);
      a0 = __builtin_amdgcn_mfma_f32_32x32x16_f16(ah, bl0, a0, 0, 0, 0);
      a0 = __builtin_amdgcn_mfma_f32_32x32x16_f16(al, bh0, a0, 0, 0, 0);
      ah = *(const h8v*)(ab0 + 2048); al = *(const h8v*)(ab0 + 3072);
      a0 = __builtin_amdgcn_mfma_f32_32x32x16_f16(ah, bh1, a0, 0, 0, 0);
      a0 = __builtin_amdgcn_mfma_f32_32x32x16_f16(ah, bl1, a0, 0, 0, 0);
      a0 = __builtin_amdgcn_mfma_f32_32x32x16_f16(al, bh1, a0, 0, 0, 0);
      ah = *(const h8v*)(ab1);        al = *(const h8v*)(ab1 + 1024);
      a1 = __builtin_amdgcn_mfma_f32_32x32x16_f16(ah, bh0, a1, 0, 0, 0);
      a1 = __builtin_amdgcn_mfma_f32_32x32x16_f16(ah, bl0, a1, 0, 0, 0);
      a1 = __builtin_amdgcn_mfma_f32_32x32x16_f16(al, bh0, a1, 0, 0, 0);
      ah = *(const h8v*)(ab1 + 2048); al = *(const h8v*)(ab1 + 3072);
      a1 = __builtin_amdgcn_mfma_f32_32x32x16_f16(ah, bh1, a1, 0, 0, 0);
      a1 = __builtin_amdgcn_mfma_f32_32x32x16_f16(ah, bl1, a1, 0, 0, 0);
      a1 = __builtin_amdgcn_mfma_f32_32x32x16_f16(al, bh1, a1, 0, 0, 0);
    }
    __builtin_amdgcn_s_barrier();
    asm volatile("" ::: "memory");
#pragma unroll
    for (int fi = 0; fi < 2; ++fi) {
      const int ftb = mr * 2 + fi;
#pragma unroll
      for (int q = 0; q < 4; ++q) {
        f4v v = fi ? f4v{a1[4 * q], a1[4 * q + 1], a1[4 * q + 2], a1[4 * q + 3]}
                   : f4v{a0[4 * q], a0[4 * q + 1], a0[4 * q + 2], a0[4 * q + 3]};
        v[0] = fmaxf(v[0], 0.f); v[1] = fmaxf(v[1], 0.f);
        v[2] = fmaxf(v[2], 0.f); v[3] = fmaxf(v[3], 0.f);
        uint2 hi, lo;
        split4s(v, hi, lo);
        const int kblk = ftb * 2 + (q >> 1);
        char* dst = hsm + (size_t)((rt * 8 + kblk) * 2) * 1024 + ((q & 1) * 32 + l31) * 16 + gg * 8;
        *(uint2*)dst = hi;
        *(uint2*)(dst + 1024) = lo;
      }
    }
    asm volatile("s_waitcnt lgkmcnt(0)" ::: "memory");
    __builtin_amdgcn_s_barrier();
    asm volatile("" ::: "memory");
    a0 = z16;
    a1 = z16;
  };

  auto wstage = [&](int i, float (&sv)[6], bool* cb) {
    ring_top(i);
    const char* wb = wsm + (i & 3) * CHUNK + lane * 16;
    if (mr == 0) {
      f16v oa = {};
#pragma unroll
      for (int kb = 0; kb < 8; ++kb) {
        h8v ah = *(const h8v*)(wb + kb * 2048);
        h8v al = *(const h8v*)(wb + kb * 2048 + 1024);
        const char* hbp = hsm + rt * 16384 + kb * 2048 + lane * 16;
        h8v bh = *(const h8v*)(hbp);
        h8v bl = *(const h8v*)(hbp + 1024);
        oa = __builtin_amdgcn_mfma_f32_32x32x16_f16(ah, bh, oa, 0, 0, 0);
        oa = __builtin_amdgcn_mfma_f32_32x32x16_f16(ah, bl, oa, 0, 0, 0);
        oa = __builtin_amdgcn_mfma_f32_32x32x16_f16(al, bh, oa, 0, 0, 0);
      }
      float m = oa[0];
#pragma unroll
      for (int r = 1; r < 16; ++r) m = fmaxf(m, oa[r]);  // pads = -60000
      m = fmaxf(m, __shfl_xor(m, 32, 64));
      if (cb) *cb = (m > 0.5f);
      sv[0] = oa[0]; sv[1] = oa[1]; sv[2] = oa[2];
      sv[3] = oa[3]; sv[4] = oa[4]; sv[5] = oa[5];
    }
  };

  hidden(0); hidden(4); hidden(8); hidden(12);
  wstage(16, s0, &c0);
  hidden(17); hidden(21); hidden(25); hidden(29); hidden(33);
  wstage(37, s1, &c1);
  hidden(38); hidden(42); hidden(46); hidden(50); hidden(54);
  wstage(58, s2, nullptr);

  if (mr == 0) {
    float r[6];
#pragma unroll
    for (int j = 0; j < 6; ++j) r[j] = c0 ? s0[j] : (c1 ? s1[j] : s2[j]);
    float* dp = out + (size_t)(tile * 128 + rt * 32 + l31) * 10;
    if (gg == 0) {  // classes 0-3, 8-9
      *(float2*)(dp)     = make_float2(r[0], r[1]);
      *(float2*)(dp + 2) = make_float2(r[2], r[3]);
      *(float2*)(dp + 8) = make_float2(r[4], r[5]);
    } else {        // classes 4-7
      *(float2*)(dp + 4) = make_float2(r[0], r[1]);
      *(float2*)(dp + 6) = make_float2(r[2], r[3]);
    }
  }
}

// ---------------------------------------------------------------------------
extern "C" void kernel_launch(void* const* d_in, const int* in_sizes, int n_in,
                              void* d_out, int out_size, void* d_ws, size_t ws_size,
                              hipStream_t stream) {
  (void)in_sizes; (void)n_in; (void)out_size; (void)ws_size;
  const float* x     = (const float*)d_in[0];
  const float* w_in  = (const float*)d_in[1];
  const float* b_in  = (const float*)d_in[2];
  const float* w_hid = (const float*)d_in[3];
  const float* b_hid = (const float*)d_in[4];
  const float* w_out = (const float*)d_in[5];
  const float* b_out = (const float*)d_in[6];
  float* out = (float*)d_out;
  char* ws = (char*)d_ws;

  (void)hipFuncSetAttribute((const void*)p1_k,
                            hipFuncAttributeMaxDynamicSharedMemorySize, P1_SMEM);
  (void)hipFuncSetAttribute((const void*)p2_k,
                            hipFuncAttributeMaxDynamicSharedMemorySize, P2_SMEM);

  prep_k<<<311, 256, 0, stream>>>(w_in, b_in, w_hid, b_hid, w_out, b_out, ws);
  p1_k<<<512, 512, P1_SMEM, stream>>>(x, ws);
  p2_k<<<512, 512, P2_SMEM, stream>>>(ws, out);
}

// Round 14
// 295.602 us; speedup vs baseline: 1.0885x; 1.0885x over previous
//
#include <hip/hip_runtime.h>

// ---------------------------------------------------------------------------
// Cascade MLP, MI355X. fp16 hi/lo split GEMMs (fp32 accum).
// FRAGMENT-MAJOR layouts; zero LDS bank conflicts (r9-verified).
// Round-14: p1 back to the r11 skeleton (best measured: 307 total) with ONE
// change: W1 stored SINGLE-fp16 (RTN) instead of split hi/lo. p1 is at ~95%
// of its VMEM-byte structural floor (r12/r13 theories refuted); the only
// lever left is fewer bytes: W1 image 1.5MB -> 768KB, per-CU VMEM 4.5 ->
// 3.77MB, MFMA/step 24 -> 16 (2-pass a*bh + a*bl; x stays split hi/lo).
// Error budget: W1-fp16-RTN adds ~2.4e-4 relative to h1 -- same order as the
// current 2.44e-4 total; threshold headroom 56x. absmax canary ~3-6e-4.
// p2 / prep structure unchanged (r12's 4-buf ring cascade, bias folded).
// ---------------------------------------------------------------------------

typedef __fp16 h2   __attribute__((ext_vector_type(2)));
typedef __fp16 h8v  __attribute__((ext_vector_type(8)));
typedef float  f4v  __attribute__((ext_vector_type(4)));
typedef float  f16v __attribute__((ext_vector_type(16)));

#define W1CH  8192    // W1 chunk: 8 single-fp16 A-frags x 1KB (k=32 x 128 feat)
#define CHUNK 16384   // split-fp16 chunk (WH/WO): 16 frags x 1KB

static constexpr unsigned OFF_W1  = 0;                       // 96 x 8KB = 786432
static constexpr unsigned OFF_WH  = 96u * W1CH;              // 786432, 56 x 16KB
static constexpr unsigned OFF_WO  = OFF_WH + 56u * CHUNK;    // 1703936, 3 x 16KB
static constexpr unsigned OFF_BIN = OFF_WO + 3u * CHUNK;     // 1753088, 128 f32
static constexpr unsigned OFF_H1  = OFF_BIN + 512;           // 1753600, 512 x 64KB

__device__ __forceinline__ unsigned bc2(h2 v) { return __builtin_bit_cast(unsigned, v); }

__device__ __forceinline__ f4v ntld4(const float* p) {
  return __builtin_nontemporal_load((const f4v*)p);
}

__device__ __forceinline__ void lds_cp16(const char* g, char* l) {
  __builtin_amdgcn_global_load_lds(
      (const __attribute__((address_space(1))) void*)g,
      (__attribute__((address_space(3))) void*)l, 16, 0, 0);
}

// p2: stage one 16KB chunk with 512 threads (2 x 16B per thread)
__device__ __forceinline__ void stage2(const char* g, char* l, int tid) {
  lds_cp16(g + tid * 16, l + tid * 16);
  lds_cp16(g + 8192 + tid * 16, l + 8192 + tid * 16);
}

// 8 fp32 (two f4v) -> hi/lo h8v fragments (kappa element order)
__device__ __forceinline__ void cvt8(f4v a, f4v b, h8v& hi, h8v& lo) {
  h2 h0 = __builtin_amdgcn_cvt_pkrtz(a[0], a[1]);
  h2 h1 = __builtin_amdgcn_cvt_pkrtz(a[2], a[3]);
  h2 h2_ = __builtin_amdgcn_cvt_pkrtz(b[0], b[1]);
  h2 h3 = __builtin_amdgcn_cvt_pkrtz(b[2], b[3]);
  h2 l0 = __builtin_amdgcn_cvt_pkrtz(a[0] - (float)h0[0], a[1] - (float)h0[1]);
  h2 l1 = __builtin_amdgcn_cvt_pkrtz(a[2] - (float)h1[0], a[3] - (float)h1[1]);
  h2 l2 = __builtin_amdgcn_cvt_pkrtz(b[0] - (float)h2_[0], b[1] - (float)h2_[1]);
  h2 l3 = __builtin_amdgcn_cvt_pkrtz(b[2] - (float)h3[0], b[3] - (float)h3[1]);
  hi = h8v{h0[0], h0[1], h1[0], h1[1], h2_[0], h2_[1], h3[0], h3[1]};
  lo = h8v{l0[0], l0[1], l1[0], l1[1], l2[0], l2[1], l3[0], l3[1]};
}

// relu'd f4v -> hi 8B + lo 8B
__device__ __forceinline__ void split4s(f4v v, uint2& hi, uint2& lo) {
  h2 a = __builtin_amdgcn_cvt_pkrtz(v[0], v[1]);
  h2 b = __builtin_amdgcn_cvt_pkrtz(v[2], v[3]);
  h2 c = __builtin_amdgcn_cvt_pkrtz(v[0] - (float)a[0], v[1] - (float)a[1]);
  h2 d = __builtin_amdgcn_cvt_pkrtz(v[2] - (float)b[0], v[3] - (float)b[1]);
  hi = make_uint2(bc2(a), bc2(b));
  lo = make_uint2(bc2(c), bc2(d));
}

__device__ __forceinline__ void split8w(const float* f, uint4& hi, uint4& lo) {
  h2 h0 = __builtin_amdgcn_cvt_pkrtz(f[0], f[1]);
  h2 h1 = __builtin_amdgcn_cvt_pkrtz(f[2], f[3]);
  h2 h2_ = __builtin_amdgcn_cvt_pkrtz(f[4], f[5]);
  h2 h3 = __builtin_amdgcn_cvt_pkrtz(f[6], f[7]);
  h2 l0 = __builtin_amdgcn_cvt_pkrtz(f[0] - (float)h0[0], f[1] - (float)h0[1]);
  h2 l1 = __builtin_amdgcn_cvt_pkrtz(f[2] - (float)h1[0], f[3] - (float)h1[1]);
  h2 l2 = __builtin_amdgcn_cvt_pkrtz(f[4] - (float)h2_[0], f[5] - (float)h2_[1]);
  h2 l3 = __builtin_amdgcn_cvt_pkrtz(f[6] - (float)h3[0], f[7] - (float)h3[1]);
  hi = make_uint4(bc2(h0), bc2(h1), bc2(h2_), bc2(h3));
  lo = make_uint4(bc2(l0), bc2(l1), bc2(l2), bc2(l3));
}

// flat items: L0-3=0..15, head0=16, L4-8=17..36, head1=37, L9-13=38..57, head2=58
__device__ __forceinline__ unsigned item_off(int it) {
  if (it >= 58) return OFF_WO + 2u * CHUNK;   // 58 + dummy tails
  if (it == 16) return OFF_WO;
  if (it == 37) return OFF_WO + CHUNK;
  int j = it - (it > 16 ? 1 : 0) - (it > 37 ? 1 : 0);
  return OFF_WH + (unsigned)j * CHUNK;
}

// ---------------------------------------------------------------------------
// prep: fragment-major images. W1 single-fp16 (RTN); WH/WO split-fp16.
// ---------------------------------------------------------------------------
__global__ __launch_bounds__(256) void prep_k(
    const float* __restrict__ w_in, const float* __restrict__ b_in,
    const float* __restrict__ w_hid, const float* __restrict__ b_hid,
    const float* __restrict__ w_out, const float* __restrict__ b_out,
    char* __restrict__ ws) {
  int idx = blockIdx.x * 256 + threadIdx.x;
  int lane = idx & 63;
  int grp = idx >> 6;
  float f[8];
  uint4 hi, lo;
  if (grp < 768) {  // W1: c(96) x mf(8), SINGLE-fp16 RTN, kappa k-perm
    int mf = grp & 7, c = grp >> 3;
    int feat = mf * 16 + (lane & 15);
    int g = lane >> 4;
    int kb = c * 32 + g * 4;
    __fp16 hf[8];
#pragma unroll
    for (int e = 0; e < 8; ++e) {
      int k = kb + (e < 4 ? e : 12 + e);   // kappa(g,e): e>=4 -> +16
      hf[e] = (__fp16)((feat < 100) ? w_in[(size_t)k * 100 + feat] : 0.f);
    }
    uint4 w = make_uint4(bc2(h2{hf[0], hf[1]}), bc2(h2{hf[2], hf[3]}),
                         bc2(h2{hf[4], hf[5]}), bc2(h2{hf[6], hf[7]}));
    char* dst = ws + OFF_W1 + (size_t)c * W1CH + (size_t)mf * 1024 + lane * 16;
    *(uint4*)dst = w;
    return;
  }
  grp -= 768;
  if (grp < 448) {  // WH: ch(56 = L*4+s) x ft(4) x j(2), 32x32 frags; bias @k=127
    int j = grp & 1, ft = (grp >> 1) & 3, ch = grp >> 3;
    int L = ch >> 2, s = ch & 3;
    int feat = ft * 32 + (lane & 31);
    int k0 = s * 32 + j * 16 + (lane >> 5) * 8;
#pragma unroll
    for (int e = 0; e < 8; ++e) {
      int k = k0 + e;
      float v;
      if (k < 100 && feat < 100)  v = w_hid[(size_t)L * 10000 + k * 100 + feat];
      else if (k == 127)          v = (feat < 100) ? b_hid[L * 100 + feat]
                                                   : (feat == 127 ? 1.f : 0.f);
      else                        v = 0.f;
      f[e] = v;
    }
    split8w(f, hi, lo);
    char* dst = ws + OFF_WH + (size_t)ch * CHUNK + (size_t)((ft * 2 + j) * 2) * 1024 + lane * 16;
    *(uint4*)dst = hi;
    *(uint4*)(dst + 1024) = lo;
    return;
  }
  grp -= 448;
  if (grp < 24) {  // WO: st(3) x kblk(8); bias row k=127, pad classes -60000
    int kb = grp & 7, st = grp >> 3;
    int cls = lane & 31;
    int k0 = kb * 16 + (lane >> 5) * 8;
#pragma unroll
    for (int e = 0; e < 8; ++e) {
      int k = k0 + e;
      float v;
      if (cls < 10 && k < 100) v = w_out[(size_t)st * 1000 + k * 10 + cls];
      else if (k == 127)       v = (cls < 10) ? b_out[st * 10 + cls] : -60000.f;
      else                     v = 0.f;
      f[e] = v;
    }
    split8w(f, hi, lo);
    char* dst = ws + OFF_WO + (size_t)st * CHUNK + (size_t)(kb * 2) * 1024 + lane * 16;
    *(uint4*)dst = hi;
    *(uint4*)(dst + 1024) = lo;
    return;
  }
  grp -= 24;
  if (grp < 2) {  // BIN: p1 epilogue bias (128 f32), bin[127] = 1.0
    int i = grp * 64 + lane;
    ((float*)(ws + OFF_BIN))[i] = (i < 100) ? b_in[i] : (i == 127 ? 1.f : 0.f);
  }
}

// ---------------------------------------------------------------------------
// p1: h1 = relu(x @ w_in + b_in) -> fragment-major h image in ws.
// 256 blocks x 1024 thr (16 waves x 16 rows = 256 rows/block, 1 block/CU).
// W1 single-fp16: stage a 16KB PAIR of chunks (one lds_cp16/thread) every
// other step; x loads dense 64B lines (kappa); 3-step x prefetch.
// FIFO (audited): prologue [S01, x0(2), x1(2), S23, x2(2)]; odd s issues
// S(s+3,s+4); every s<=93 waits vmcnt(5); s94 -> 2; s95 -> 0.
// ---------------------------------------------------------------------------
#define P1_SMEM (3 * 16384)  // 49152: 3 bufs x (2 chunks x 8KB)

__global__ __launch_bounds__(1024, 4) void p1_k(const float* __restrict__ x,
                                                char* __restrict__ ws) {
  extern __shared__ __align__(16) char sm[];
  const int tid = threadIdx.x;
  const int lane = tid & 63, wid = tid >> 6;   // wid 0..15
  const int l15 = lane & 15, g = lane >> 4;
  const int tile = blockIdx.x;  // 256 rows
  const char* w1g = ws + OFF_W1;
  const float* xr = x + (size_t)(tile * 256 + wid * 16 + l15) * 3072;

  auto stW = [&](int t) {  // stage chunk pair t (chunks 2t, 2t+1) -> buf t%3
    lds_cp16(w1g + (size_t)t * 16384 + tid * 16, sm + (t % 3) * 16384 + tid * 16);
  };

  f4v xP[2], xQ[2], xR[2];
  auto ldx = [&](int s, f4v (&xa)[2]) {
    const int o = s * 32 + g * 4;
    xa[0] = ntld4(xr + o); xa[1] = ntld4(xr + o + 16);
  };

  // prologue FIFO: S01(1), x0(2), x1(2), S23(1), x2(2) = 8 outstanding
  stW(0);
  __builtin_amdgcn_sched_barrier(0);
  ldx(0, xP);
  __builtin_amdgcn_sched_barrier(0);
  ldx(1, xQ);
  __builtin_amdgcn_sched_barrier(0);
  stW(1);
  __builtin_amdgcn_sched_barrier(0);
  ldx(2, xR);
  __builtin_amdgcn_sched_barrier(0);

  f4v acc[8] = {};

  auto step = [&](int s, f4v (&xa)[2]) {
    if (s <= 93)      asm volatile("s_waitcnt vmcnt(5)" ::: "memory");
    else if (s == 94) asm volatile("s_waitcnt vmcnt(2)" ::: "memory");
    else              asm volatile("s_waitcnt vmcnt(0)" ::: "memory");
    __builtin_amdgcn_s_barrier();
    asm volatile("" ::: "memory");

    h8v bh, bl;
    cvt8(xa[0], xa[1], bh, bl);
    // issue order: S (odd steps) BEFORE x (FIFO drain pairing)
    if ((s & 1) && (s + 3 < 96)) stW((s + 3) >> 1);
    __builtin_amdgcn_sched_barrier(0);
    if (s + 3 < 96) ldx(s + 3, xa);
    __builtin_amdgcn_sched_barrier(0);

    const char* ab = sm + ((s >> 1) % 3) * 16384 + (s & 1) * 8192 + lane * 16;
#pragma unroll
    for (int mf = 0; mf < 8; ++mf) {
      h8v a = *(const h8v*)(ab + mf * 1024);
      acc[mf] = __builtin_amdgcn_mfma_f32_16x16x32_f16(a, bh, acc[mf], 0, 0, 0);
      acc[mf] = __builtin_amdgcn_mfma_f32_16x16x32_f16(a, bl, acc[mf], 0, 0, 0);
    }
  };

#pragma unroll 1
  for (int s3 = 0; s3 < 96; s3 += 3) {
    step(s3, xP);
    step(s3 + 1, xQ);
    step(s3 + 2, xR);
  }

  // epilogue: bias + relu + split -> h frags (16x16 C/D: col=l15=row,
  // feature = mf*16 + g*4 + q). Global row R = tile*256 + wid*16 + l15.
  const float* bp = (const float*)(ws + OFF_BIN);
  const int p2tile = tile * 2 + (wid >> 3);   // R >> 7
  const int rt = (wid >> 1) & 3;              // (R >> 5) & 3
  const int l31 = (wid & 1) * 16 + l15;       // R & 31
  char* hb = ws + OFF_H1 + (size_t)p2tile * 65536;
#pragma unroll
  for (int mf = 0; mf < 8; ++mf) {
    f4v bi = *(const f4v*)(bp + mf * 16 + g * 4);
    f4v v = acc[mf] + bi;
    v[0] = fmaxf(v[0], 0.f); v[1] = fmaxf(v[1], 0.f);
    v[2] = fmaxf(v[2], 0.f); v[3] = fmaxf(v[3], 0.f);
    uint2 hi, lo;
    split4s(v, hi, lo);
    // B-frag slot: kblk=mf, g'=(g>>1), e=(g&1)*4+q
    char* dst = hb + (size_t)(rt * 8 + mf) * 2048 + (g >> 1) * 512 + l31 * 16 + (g & 1) * 8;
    *(uint2*)dst = hi;
    *(uint2*)(dst + 1024) = lo;
  }
}

// ---------------------------------------------------------------------------
// p2: cascade + heads + early-exit select (r12's 4-buf ring, unchanged).
// ---------------------------------------------------------------------------
#define P2_SMEM (65536 + 4 * CHUNK)  // 131072

__global__ __launch_bounds__(512, 2) void p2_k(char* __restrict__ ws,
                                               float* __restrict__ out) {
  extern __shared__ __align__(16) char sm[];
  char* hsm = sm;             // h frags, 64KB
  char* wsm = sm + 65536;     // 4 chunk bufs
  const int tid = threadIdx.x;
  const int lane = tid & 63, wid = tid >> 6;
  const int mr = wid & 1, rt = wid >> 1;
  const int l31 = lane & 31, gg = lane >> 5;
  const int tile = blockIdx.x;

  {  // prologue DMA (per-lane FIFO): h(8), i0(2), i1(2), i2(2)
    const char* hg = ws + OFF_H1 + (size_t)tile * 65536;
#pragma unroll
    for (int i = 0; i < 8; ++i)
      lds_cp16(hg + i * 8192 + tid * 16, hsm + i * 8192 + tid * 16);
    __builtin_amdgcn_sched_barrier(0);
    stage2(ws + item_off(0), wsm, tid);
    stage2(ws + item_off(1), wsm + CHUNK, tid);
    stage2(ws + item_off(2), wsm + 2 * CHUNK, tid);
  }

  const f16v z16 = {};
  f16v a0 = {}, a1 = {};
  float s0[6], s1[6], s2[6];
  bool c0 = false, c1 = false;

  auto ring_top = [&](int i) {
    asm volatile("s_waitcnt vmcnt(4)" ::: "memory");
    __builtin_amdgcn_s_barrier();
    asm volatile("" ::: "memory");
    stage2(ws + item_off(i + 3), wsm + ((i + 3) & 3) * CHUNK, tid);
  };

  auto hidden = [&](int base) {
#pragma unroll
    for (int ss = 0; ss < 4; ++ss) {
      ring_top(base + ss);
      const char* wb = wsm + ((base + ss) & 3) * CHUNK + lane * 16;
      const char* hbp = hsm + rt * 16384 + ss * 4096 + lane * 16;
      h8v bh0 = *(const h8v*)(hbp);
      h8v bl0 = *(const h8v*)(hbp + 1024);
      h8v bh1 = *(const h8v*)(hbp + 2048);
      h8v bl1 = *(const h8v*)(hbp + 3072);
      const char* ab0 = wb + (mr * 2) * 4096;
      const char* ab1 = ab0 + 4096;
      h8v ah, al;
      ah = *(const h8v*)(ab0);        al = *(const h8v*)(ab0 + 1024);
      a0 = __builtin_amdgcn_mfma_f32_32x32x16_f16(ah, bh0, a0, 0, 0, 0);
      a0 = __builtin_amdgcn_mfma_f32_32x32x16_f16(ah, bl0, a0, 0, 0, 0);
      a0 = __builtin_amdgcn_mfma_f32_32x32x16_f16(al, bh0, a0, 0, 0, 0);
      ah = *(const h8v*)(ab0 + 2048); al = *(const h8v*)(ab0 + 3072);
      a0 = __builtin_amdgcn_mfma_f32_32x32x16_f16(ah, bh1, a0, 0, 0, 0);
      a0 = __builtin_amdgcn_mfma_f32_32x32x16_f16(ah, bl1, a0, 0, 0, 0);
      a0 = __builtin_amdgcn_mfma_f32_32x32x16_f16(al, bh1, a0, 0, 0, 0);
      ah = *(const h8v*)(ab1);        al = *(const h8v*)(ab1 + 1024);
      a1 = __builtin_amdgcn_mfma_f32_32x32x16_f16(ah, bh0, a1, 0, 0, 0);
      a1 = __builtin_amdgcn_mfma_f32_32x32x16_f16(ah, bl0, a1, 0, 0, 0);
      a1 = __builtin_amdgcn_mfma_f32_32x32x16_f16(al, bh0, a1, 0, 0, 0);
      ah = *(const h8v*)(ab1 + 2048); al = *(const h8v*)(ab1 + 3072);
      a1 = __builtin_amdgcn_mfma_f32_32x32x16_f16(ah, bh1, a1, 0, 0, 0);
      a1 = __builtin_amdgcn_mfma_f32_32x32x16_f16(ah, bl1, a1, 0, 0, 0);
      a1 = __builtin_amdgcn_mfma_f32_32x32x16_f16(al, bh1, a1, 0, 0, 0);
    }
    __builtin_amdgcn_s_barrier();
    asm volatile("" ::: "memory");
#pragma unroll
    for (int fi = 0; fi < 2; ++fi) {
      const int ftb = mr * 2 + fi;
#pragma unroll
      for (int q = 0; q < 4; ++q) {
        f4v v = fi ? f4v{a1[4 * q], a1[4 * q + 1], a1[4 * q + 2], a1[4 * q + 3]}
                   : f4v{a0[4 * q], a0[4 * q + 1], a0[4 * q + 2], a0[4 * q + 3]};
        v[0] = fmaxf(v[0], 0.f); v[1] = fmaxf(v[1], 0.f);
        v[2] = fmaxf(v[2], 0.f); v[3] = fmaxf(v[3], 0.f);
        uint2 hi, lo;
        split4s(v, hi, lo);
        const int kblk = ftb * 2 + (q >> 1);
        char* dst = hsm + (size_t)((rt * 8 + kblk) * 2) * 1024 + ((q & 1) * 32 + l31) * 16 + gg * 8;
        *(uint2*)dst = hi;
        *(uint2*)(dst + 1024) = lo;
      }
    }
    asm volatile("s_waitcnt lgkmcnt(0)" ::: "memory");
    __builtin_amdgcn_s_barrier();
    asm volatile("" ::: "memory");
    a0 = z16;
    a1 = z16;
  };

  auto wstage = [&](int i, float (&sv)[6], bool* cb) {
    ring_top(i);
    const char* wb = wsm + (i & 3) * CHUNK + lane * 16;
    if (mr == 0) {
      f16v oa = {};
#pragma unroll
      for (int kb = 0; kb < 8; ++kb) {
        h8v ah = *(const h8v*)(wb + kb * 2048);
        h8v al = *(const h8v*)(wb + kb * 2048 + 1024);
        const char* hbp = hsm + rt * 16384 + kb * 2048 + lane * 16;
        h8v bh = *(const h8v*)(hbp);
        h8v bl = *(const h8v*)(hbp + 1024);
        oa = __builtin_amdgcn_mfma_f32_32x32x16_f16(ah, bh, oa, 0, 0, 0);
        oa = __builtin_amdgcn_mfma_f32_32x32x16_f16(ah, bl, oa, 0, 0, 0);
        oa = __builtin_amdgcn_mfma_f32_32x32x16_f16(al, bh, oa, 0, 0, 0);
      }
      float m = oa[0];
#pragma unroll
      for (int r = 1; r < 16; ++r) m = fmaxf(m, oa[r]);  // pads = -60000
      m = fmaxf(m, __shfl_xor(m, 32, 64));
      if (cb) *cb = (m > 0.5f);
      sv[0] = oa[0]; sv[1] = oa[1]; sv[2] = oa[2];
      sv[3] = oa[3]; sv[4] = oa[4]; sv[5] = oa[5];
    }
  };

  hidden(0); hidden(4); hidden(8); hidden(12);
  wstage(16, s0, &c0);
  hidden(17); hidden(21); hidden(25); hidden(29); hidden(33);
  wstage(37, s1, &c1);
  hidden(38); hidden(42); hidden(46); hidden(50); hidden(54);
  wstage(58, s2, nullptr);

  if (mr == 0) {
    float r[6];
#pragma unroll
    for (int j = 0; j < 6; ++j) r[j] = c0 ? s0[j] : (c1 ? s1[j] : s2[j]);
    float* dp = out + (size_t)(tile * 128 + rt * 32 + l31) * 10;
    if (gg == 0) {  // classes 0-3, 8-9
      *(float2*)(dp)     = make_float2(r[0], r[1]);
      *(float2*)(dp + 2) = make_float2(r[2], r[3]);
      *(float2*)(dp + 8) = make_float2(r[4], r[5]);
    } else {        // classes 4-7
      *(float2*)(dp + 4) = make_float2(r[0], r[1]);
      *(float2*)(dp + 6) = make_float2(r[2], r[3]);
    }
  }
}

// ---------------------------------------------------------------------------
extern "C" void kernel_launch(void* const* d_in, const int* in_sizes, int n_in,
                              void* d_out, int out_size, void* d_ws, size_t ws_size,
                              hipStream_t stream) {
  (void)in_sizes; (void)n_in; (void)out_size; (void)ws_size;
  const float* x     = (const float*)d_in[0];
  const float* w_in  = (const float*)d_in[1];
  const float* b_in  = (const float*)d_in[2];
  const float* w_hid = (const float*)d_in[3];
  const float* b_hid = (const float*)d_in[4];
  const float* w_out = (const float*)d_in[5];
  const float* b_out = (const float*)d_in[6];
  float* out = (float*)d_out;
  char* ws = (char*)d_ws;

  (void)hipFuncSetAttribute((const void*)p1_k,
                            hipFuncAttributeMaxDynamicSharedMemorySize, P1_SMEM);
  (void)hipFuncSetAttribute((const void*)p2_k,
                            hipFuncAttributeMaxDynamicSharedMemorySize, P2_SMEM);

  prep_k<<<311, 256, 0, stream>>>(w_in, b_in, w_hid, b_hid, w_out, b_out, ws);
  p1_k<<<256, 1024, P1_SMEM, stream>>>(x, ws);
  p2_k<<<512, 512, P2_SMEM, stream>>>(ws, out);
}

// Round 15
// 276.192 us; speedup vs baseline: 1.1650x; 1.0703x over previous
//
#include <hip/hip_runtime.h>

// ---------------------------------------------------------------------------
// Cascade MLP, MI355X. MFMA GEMMs, fp32 accum. FRAGMENT-MAJOR layouts; zero
// LDS bank conflicts (r9-verified). x stays split-fp16 hi/lo (precision
// anchor); ALL weights now single-fp16 RTN (r14 proved W1-fp16: +1.7e-3
// absmax, -12us; r15 extends to WH/WO -- p2 is LDS-BW bound: 96KB reads/item
// for 16KB of weights; fp16 weights halve weight LDS traffic AND MFMA count).
// h image stays split hi/lo. Bias folded via h[127]=1, weight row k=127.
// p1: r14 verbatim (295.6us kernel). p2: 8KB single-fp16 chunks, 4-buf ring.
// absmax canary: expect 4-9e-3 (threshold 1.375e-2); FAIL => revert WH split.
// ---------------------------------------------------------------------------

typedef __fp16 h2   __attribute__((ext_vector_type(2)));
typedef __fp16 h8v  __attribute__((ext_vector_type(8)));
typedef float  f4v  __attribute__((ext_vector_type(4)));
typedef float  f16v __attribute__((ext_vector_type(16)));

#define W1CH  8192    // W1 chunk: 8 fp16 16x16 A-frags x 1KB (k=32 x 128 feat)
#define WHCH  8192    // WH/WO chunk: 8 fp16 32x32 A-frags x 1KB

static constexpr unsigned OFF_W1  = 0;                       // 96 x 8KB
static constexpr unsigned OFF_WH  = 96u * W1CH;              // 786432, 56 x 8KB
static constexpr unsigned OFF_WO  = OFF_WH + 56u * WHCH;     // 1245184, 3 x 8KB
static constexpr unsigned OFF_BIN = OFF_WO + 3u * WHCH;      // 1269760, 128 f32
static constexpr unsigned OFF_H1  = OFF_BIN + 512;           // 1270272, 512 x 64KB

__device__ __forceinline__ unsigned bc2(h2 v) { return __builtin_bit_cast(unsigned, v); }

__device__ __forceinline__ f4v ntld4(const float* p) {
  return __builtin_nontemporal_load((const f4v*)p);
}

__device__ __forceinline__ void lds_cp16(const char* g, char* l) {
  __builtin_amdgcn_global_load_lds(
      (const __attribute__((address_space(1))) void*)g,
      (__attribute__((address_space(3))) void*)l, 16, 0, 0);
}

// 8 fp32 (two f4v) -> hi/lo h8v fragments (kappa element order)
__device__ __forceinline__ void cvt8(f4v a, f4v b, h8v& hi, h8v& lo) {
  h2 h0 = __builtin_amdgcn_cvt_pkrtz(a[0], a[1]);
  h2 h1 = __builtin_amdgcn_cvt_pkrtz(a[2], a[3]);
  h2 h2_ = __builtin_amdgcn_cvt_pkrtz(b[0], b[1]);
  h2 h3 = __builtin_amdgcn_cvt_pkrtz(b[2], b[3]);
  h2 l0 = __builtin_amdgcn_cvt_pkrtz(a[0] - (float)h0[0], a[1] - (float)h0[1]);
  h2 l1 = __builtin_amdgcn_cvt_pkrtz(a[2] - (float)h1[0], a[3] - (float)h1[1]);
  h2 l2 = __builtin_amdgcn_cvt_pkrtz(b[0] - (float)h2_[0], b[1] - (float)h2_[1]);
  h2 l3 = __builtin_amdgcn_cvt_pkrtz(b[2] - (float)h3[0], b[3] - (float)h3[1]);
  hi = h8v{h0[0], h0[1], h1[0], h1[1], h2_[0], h2_[1], h3[0], h3[1]};
  lo = h8v{l0[0], l0[1], l1[0], l1[1], l2[0], l2[1], l3[0], l3[1]};
}

// relu'd f4v -> hi 8B + lo 8B
__device__ __forceinline__ void split4s(f4v v, uint2& hi, uint2& lo) {
  h2 a = __builtin_amdgcn_cvt_pkrtz(v[0], v[1]);
  h2 b = __builtin_amdgcn_cvt_pkrtz(v[2], v[3]);
  h2 c = __builtin_amdgcn_cvt_pkrtz(v[0] - (float)a[0], v[1] - (float)a[1]);
  h2 d = __builtin_amdgcn_cvt_pkrtz(v[2] - (float)b[0], v[3] - (float)b[1]);
  hi = make_uint2(bc2(a), bc2(b));
  lo = make_uint2(bc2(c), bc2(d));
}

// flat items: L0-3=0..15, head0=16, L4-8=17..36, head1=37, L9-13=38..57, head2=58
__device__ __forceinline__ unsigned item_off(int it) {
  if (it >= 58) return OFF_WO + 2u * WHCH;   // 58 + dummy tails
  if (it == 16) return OFF_WO;
  if (it == 37) return OFF_WO + WHCH;
  int j = it - (it > 16 ? 1 : 0) - (it > 37 ? 1 : 0);
  return OFF_WH + (unsigned)j * WHCH;
}

// ---------------------------------------------------------------------------
// prep: fragment-major images, ALL weights single-fp16 RTN.
// ---------------------------------------------------------------------------
__global__ __launch_bounds__(256) void prep_k(
    const float* __restrict__ w_in, const float* __restrict__ b_in,
    const float* __restrict__ w_hid, const float* __restrict__ b_hid,
    const float* __restrict__ w_out, const float* __restrict__ b_out,
    char* __restrict__ ws) {
  int idx = blockIdx.x * 256 + threadIdx.x;
  int lane = idx & 63;
  int grp = idx >> 6;
  __fp16 hf[8];
  if (grp < 768) {  // W1: c(96) x mf(8) 16x16 A-frags, kappa k-perm
    int mf = grp & 7, c = grp >> 3;
    int feat = mf * 16 + (lane & 15);
    int g = lane >> 4;
    int kb = c * 32 + g * 4;
#pragma unroll
    for (int e = 0; e < 8; ++e) {
      int k = kb + (e < 4 ? e : 12 + e);   // kappa(g,e): e>=4 -> +16
      hf[e] = (__fp16)((feat < 100) ? w_in[(size_t)k * 100 + feat] : 0.f);
    }
    uint4 w = make_uint4(bc2(h2{hf[0], hf[1]}), bc2(h2{hf[2], hf[3]}),
                         bc2(h2{hf[4], hf[5]}), bc2(h2{hf[6], hf[7]}));
    *(uint4*)(ws + OFF_W1 + (size_t)c * W1CH + (size_t)mf * 1024 + lane * 16) = w;
    return;
  }
  grp -= 768;
  if (grp < 448) {  // WH: ch(56 = L*4+s) x ft(4) x j(2), 32x32 frags; bias @k=127
    int j = grp & 1, ft = (grp >> 1) & 3, ch = grp >> 3;
    int L = ch >> 2, s = ch & 3;
    int feat = ft * 32 + (lane & 31);
    int k0 = s * 32 + j * 16 + (lane >> 5) * 8;
#pragma unroll
    for (int e = 0; e < 8; ++e) {
      int k = k0 + e;
      float v;
      if (k < 100 && feat < 100)  v = w_hid[(size_t)L * 10000 + k * 100 + feat];
      else if (k == 127)          v = (feat < 100) ? b_hid[L * 100 + feat]
                                                   : (feat == 127 ? 1.f : 0.f);
      else                        v = 0.f;
      hf[e] = (__fp16)v;
    }
    uint4 w = make_uint4(bc2(h2{hf[0], hf[1]}), bc2(h2{hf[2], hf[3]}),
                         bc2(h2{hf[4], hf[5]}), bc2(h2{hf[6], hf[7]}));
    *(uint4*)(ws + OFF_WH + (size_t)ch * WHCH + (size_t)(ft * 2 + j) * 1024 + lane * 16) = w;
    return;
  }
  grp -= 448;
  if (grp < 24) {  // WO: st(3) x kblk(8); bias row k=127, pad classes -60000
    int kb = grp & 7, st = grp >> 3;
    int cls = lane & 31;
    int k0 = kb * 16 + (lane >> 5) * 8;
#pragma unroll
    for (int e = 0; e < 8; ++e) {
      int k = k0 + e;
      float v;
      if (cls < 10 && k < 100) v = w_out[(size_t)st * 1000 + k * 10 + cls];
      else if (k == 127)       v = (cls < 10) ? b_out[st * 10 + cls] : -60000.f;
      else                     v = 0.f;
      hf[e] = (__fp16)v;
    }
    uint4 w = make_uint4(bc2(h2{hf[0], hf[1]}), bc2(h2{hf[2], hf[3]}),
                         bc2(h2{hf[4], hf[5]}), bc2(h2{hf[6], hf[7]}));
    *(uint4*)(ws + OFF_WO + (size_t)st * WHCH + (size_t)kb * 1024 + lane * 16) = w;
    return;
  }
  grp -= 24;
  if (grp < 2) {  // BIN: p1 epilogue bias (128 f32), bin[127] = 1.0
    int i = grp * 64 + lane;
    ((float*)(ws + OFF_BIN))[i] = (i < 100) ? b_in[i] : (i == 127 ? 1.f : 0.f);
  }
}

// ---------------------------------------------------------------------------
// p1: h1 = relu(x @ w_in + b_in) -> fragment-major h image in ws.
// 256 blocks x 1024 thr (16 waves x 16 rows). r14 verbatim (measured-good).
// ---------------------------------------------------------------------------
#define P1_SMEM (3 * 16384)  // 49152: 3 bufs x (2 chunks x 8KB)

__global__ __launch_bounds__(1024, 4) void p1_k(const float* __restrict__ x,
                                                char* __restrict__ ws) {
  extern __shared__ __align__(16) char sm[];
  const int tid = threadIdx.x;
  const int lane = tid & 63, wid = tid >> 6;   // wid 0..15
  const int l15 = lane & 15, g = lane >> 4;
  const int tile = blockIdx.x;  // 256 rows
  const char* w1g = ws + OFF_W1;
  const float* xr = x + (size_t)(tile * 256 + wid * 16 + l15) * 3072;

  auto stW = [&](int t) {  // stage chunk pair t (chunks 2t, 2t+1) -> buf t%3
    lds_cp16(w1g + (size_t)t * 16384 + tid * 16, sm + (t % 3) * 16384 + tid * 16);
  };

  f4v xP[2], xQ[2], xR[2];
  auto ldx = [&](int s, f4v (&xa)[2]) {
    const int o = s * 32 + g * 4;
    xa[0] = ntld4(xr + o); xa[1] = ntld4(xr + o + 16);
  };

  // prologue FIFO: S01(1), x0(2), x1(2), S23(1), x2(2) = 8 outstanding
  stW(0);
  __builtin_amdgcn_sched_barrier(0);
  ldx(0, xP);
  __builtin_amdgcn_sched_barrier(0);
  ldx(1, xQ);
  __builtin_amdgcn_sched_barrier(0);
  stW(1);
  __builtin_amdgcn_sched_barrier(0);
  ldx(2, xR);
  __builtin_amdgcn_sched_barrier(0);

  f4v acc[8] = {};

  auto step = [&](int s, f4v (&xa)[2]) {
    if (s <= 93)      asm volatile("s_waitcnt vmcnt(5)" ::: "memory");
    else if (s == 94) asm volatile("s_waitcnt vmcnt(2)" ::: "memory");
    else              asm volatile("s_waitcnt vmcnt(0)" ::: "memory");
    __builtin_amdgcn_s_barrier();
    asm volatile("" ::: "memory");

    h8v bh, bl;
    cvt8(xa[0], xa[1], bh, bl);
    if ((s & 1) && (s + 3 < 96)) stW((s + 3) >> 1);
    __builtin_amdgcn_sched_barrier(0);
    if (s + 3 < 96) ldx(s + 3, xa);
    __builtin_amdgcn_sched_barrier(0);

    const char* ab = sm + ((s >> 1) % 3) * 16384 + (s & 1) * 8192 + lane * 16;
#pragma unroll
    for (int mf = 0; mf < 8; ++mf) {
      h8v a = *(const h8v*)(ab + mf * 1024);
      acc[mf] = __builtin_amdgcn_mfma_f32_16x16x32_f16(a, bh, acc[mf], 0, 0, 0);
      acc[mf] = __builtin_amdgcn_mfma_f32_16x16x32_f16(a, bl, acc[mf], 0, 0, 0);
    }
  };

#pragma unroll 1
  for (int s3 = 0; s3 < 96; s3 += 3) {
    step(s3, xP);
    step(s3 + 1, xQ);
    step(s3 + 2, xR);
  }

  // epilogue: bias + relu + split -> h frags (16x16 C/D).
  const float* bp = (const float*)(ws + OFF_BIN);
  const int p2tile = tile * 2 + (wid >> 3);   // R >> 7
  const int rt = (wid >> 1) & 3;              // (R >> 5) & 3
  const int l31 = (wid & 1) * 16 + l15;       // R & 31
  char* hb = ws + OFF_H1 + (size_t)p2tile * 65536;
#pragma unroll
  for (int mf = 0; mf < 8; ++mf) {
    f4v bi = *(const f4v*)(bp + mf * 16 + g * 4);
    f4v v = acc[mf] + bi;
    v[0] = fmaxf(v[0], 0.f); v[1] = fmaxf(v[1], 0.f);
    v[2] = fmaxf(v[2], 0.f); v[3] = fmaxf(v[3], 0.f);
    uint2 hi, lo;
    split4s(v, hi, lo);
    char* dst = hb + (size_t)(rt * 8 + mf) * 2048 + (g >> 1) * 512 + l31 * 16 + (g & 1) * 8;
    *(uint2*)dst = hi;
    *(uint2*)(dst + 1024) = lo;
  }
}

// ---------------------------------------------------------------------------
// p2: cascade + heads + early-exit select. Single-fp16 weight chunks (8KB),
// 4-buf ring 3-ahead; h split hi/lo in LDS. 512 blocks x 512 thr.
// ---------------------------------------------------------------------------
#define P2_SMEM (65536 + 4 * WHCH)  // 98304

__global__ __launch_bounds__(512, 2) void p2_k(char* __restrict__ ws,
                                               float* __restrict__ out) {
  extern __shared__ __align__(16) char sm[];
  char* hsm = sm;             // h frags, 64KB
  char* wsm = sm + 65536;     // 4 x 8KB chunk bufs
  const int tid = threadIdx.x;
  const int lane = tid & 63, wid = tid >> 6;
  const int mr = wid & 1, rt = wid >> 1;
  const int l31 = lane & 31, gg = lane >> 5;
  const int tile = blockIdx.x;

  auto stage1 = [&](const char* g, char* l) {  // 8KB: 1 x 16B per thread
    lds_cp16(g + tid * 16, l + tid * 16);
  };

  {  // prologue DMA (per-lane FIFO): h(8), i0(1), i1(1), i2(1)
    const char* hg = ws + OFF_H1 + (size_t)tile * 65536;
#pragma unroll
    for (int i = 0; i < 8; ++i)
      lds_cp16(hg + i * 8192 + tid * 16, hsm + i * 8192 + tid * 16);
    __builtin_amdgcn_sched_barrier(0);
    stage1(ws + item_off(0), wsm);
    stage1(ws + item_off(1), wsm + WHCH);
    stage1(ws + item_off(2), wsm + 2 * WHCH);
  }

  const f16v z16 = {};
  f16v a0 = {}, a1 = {};
  float s0[6], s1[6], s2[6];
  bool c0 = false, c1 = false;

  // ring: wait stage(i) done (leaves i+1, i+2 = 2 loads) -> barrier ->
  // stage(i+3) into buf (i+3)&3 == (i-1)&3 (readers done before barrier).
  auto ring_top = [&](int i) {
    asm volatile("s_waitcnt vmcnt(2)" ::: "memory");
    __builtin_amdgcn_s_barrier();
    asm volatile("" ::: "memory");
    stage1(ws + item_off(i + 3), wsm + ((i + 3) & 3) * WHCH);
  };

  auto hidden = [&](int base) {
#pragma unroll
    for (int ss = 0; ss < 4; ++ss) {
      ring_top(base + ss);
      const char* wb = wsm + ((base + ss) & 3) * WHCH + lane * 16;
      const char* hbp = hsm + rt * 16384 + ss * 4096 + lane * 16;
      h8v bh0 = *(const h8v*)(hbp);
      h8v bl0 = *(const h8v*)(hbp + 1024);
      h8v bh1 = *(const h8v*)(hbp + 2048);
      h8v bl1 = *(const h8v*)(hbp + 3072);
      const char* a0p = wb + (mr * 2) * 2048;       // ftb = mr*2
      const char* a1p = wb + (mr * 2 + 1) * 2048;   // ftb = mr*2+1
      h8v a;
      a = *(const h8v*)(a0p);
      a0 = __builtin_amdgcn_mfma_f32_32x32x16_f16(a, bh0, a0, 0, 0, 0);
      a0 = __builtin_amdgcn_mfma_f32_32x32x16_f16(a, bl0, a0, 0, 0, 0);
      a = *(const h8v*)(a0p + 1024);
      a0 = __builtin_amdgcn_mfma_f32_32x32x16_f16(a, bh1, a0, 0, 0, 0);
      a0 = __builtin_amdgcn_mfma_f32_32x32x16_f16(a, bl1, a0, 0, 0, 0);
      a = *(const h8v*)(a1p);
      a1 = __builtin_amdgcn_mfma_f32_32x32x16_f16(a, bh0, a1, 0, 0, 0);
      a1 = __builtin_amdgcn_mfma_f32_32x32x16_f16(a, bl0, a1, 0, 0, 0);
      a = *(const h8v*)(a1p + 1024);
      a1 = __builtin_amdgcn_mfma_f32_32x32x16_f16(a, bh1, a1, 0, 0, 0);
      a1 = __builtin_amdgcn_mfma_f32_32x32x16_f16(a, bl1, a1, 0, 0, 0);
    }
    __builtin_amdgcn_s_barrier();
    asm volatile("" ::: "memory");
#pragma unroll
    for (int fi = 0; fi < 2; ++fi) {
      const int ftb = mr * 2 + fi;
#pragma unroll
      for (int q = 0; q < 4; ++q) {
        f4v v = fi ? f4v{a1[4 * q], a1[4 * q + 1], a1[4 * q + 2], a1[4 * q + 3]}
                   : f4v{a0[4 * q], a0[4 * q + 1], a0[4 * q + 2], a0[4 * q + 3]};
        v[0] = fmaxf(v[0], 0.f); v[1] = fmaxf(v[1], 0.f);
        v[2] = fmaxf(v[2], 0.f); v[3] = fmaxf(v[3], 0.f);
        uint2 hi, lo;
        split4s(v, hi, lo);
        const int kblk = ftb * 2 + (q >> 1);
        char* dst = hsm + (size_t)((rt * 8 + kblk) * 2) * 1024 + ((q & 1) * 32 + l31) * 16 + gg * 8;
        *(uint2*)dst = hi;
        *(uint2*)(dst + 1024) = lo;
      }
    }
    asm volatile("s_waitcnt lgkmcnt(0)" ::: "memory");
    __builtin_amdgcn_s_barrier();
    asm volatile("" ::: "memory");
    a0 = z16;
    a1 = z16;
  };

  auto wstage = [&](int i, float (&sv)[6], bool* cb) {
    ring_top(i);
    const char* wb = wsm + (i & 3) * WHCH + lane * 16;
    if (mr == 0) {
      f16v oa = {};
#pragma unroll
      for (int kb = 0; kb < 8; ++kb) {
        h8v a = *(const h8v*)(wb + kb * 1024);
        const char* hbp = hsm + rt * 16384 + kb * 2048 + lane * 16;
        h8v bh = *(const h8v*)(hbp);
        h8v bl = *(const h8v*)(hbp + 1024);
        oa = __builtin_amdgcn_mfma_f32_32x32x16_f16(a, bh, oa, 0, 0, 0);
        oa = __builtin_amdgcn_mfma_f32_32x32x16_f16(a, bl, oa, 0, 0, 0);
      }
      float m = oa[0];
#pragma unroll
      for (int r = 1; r < 16; ++r) m = fmaxf(m, oa[r]);  // pads = -60000
      m = fmaxf(m, __shfl_xor(m, 32, 64));
      if (cb) *cb = (m > 0.5f);
      sv[0] = oa[0]; sv[1] = oa[1]; sv[2] = oa[2];
      sv[3] = oa[3]; sv[4] = oa[4]; sv[5] = oa[5];
    }
  };

  hidden(0); hidden(4); hidden(8); hidden(12);
  wstage(16, s0, &c0);
  hidden(17); hidden(21); hidden(25); hidden(29); hidden(33);
  wstage(37, s1, &c1);
  hidden(38); hidden(42); hidden(46); hidden(50); hidden(54);
  wstage(58, s2, nullptr);

  if (mr == 0) {
    float r[6];
#pragma unroll
    for (int j = 0; j < 6; ++j) r[j] = c0 ? s0[j] : (c1 ? s1[j] : s2[j]);
    float* dp = out + (size_t)(tile * 128 + rt * 32 + l31) * 10;
    if (gg == 0) {  // classes 0-3, 8-9
      *(float2*)(dp)     = make_float2(r[0], r[1]);
      *(float2*)(dp + 2) = make_float2(r[2], r[3]);
      *(float2*)(dp + 8) = make_float2(r[4], r[5]);
    } else {        // classes 4-7
      *(float2*)(dp + 4) = make_float2(r[0], r[1]);
      *(float2*)(dp + 6) = make_float2(r[2], r[3]);
    }
  }
}

// ---------------------------------------------------------------------------
extern "C" void kernel_launch(void* const* d_in, const int* in_sizes, int n_in,
                              void* d_out, int out_size, void* d_ws, size_t ws_size,
                              hipStream_t stream) {
  (void)in_sizes; (void)n_in; (void)out_size; (void)ws_size;
  const float* x     = (const float*)d_in[0];
  const float* w_in  = (const float*)d_in[1];
  const float* b_in  = (const float*)d_in[2];
  const float* w_hid = (const float*)d_in[3];
  const float* b_hid = (const float*)d_in[4];
  const float* w_out = (const float*)d_in[5];
  const float* b_out = (const float*)d_in[6];
  float* out = (float*)d_out;
  char* ws = (char*)d_ws;

  (void)hipFuncSetAttribute((const void*)p1_k,
                            hipFuncAttributeMaxDynamicSharedMemorySize, P1_SMEM);
  (void)hipFuncSetAttribute((const void*)p2_k,
                            hipFuncAttributeMaxDynamicSharedMemorySize, P2_SMEM);

  prep_k<<<311, 256, 0, stream>>>(w_in, b_in, w_hid, b_hid, w_out, b_out, ws);
  p1_k<<<256, 1024, P1_SMEM, stream>>>(x, ws);
  p2_k<<<512, 512, P2_SMEM, stream>>>(ws, out);
}